// Round 7
// baseline (77.571 us; speedup 1.0000x reference)
//
#include <hip/hip_runtime.h>
#include <hip/hip_bf16.h>

typedef __bf16 bf16_t;
typedef __attribute__((ext_vector_type(8))) __bf16 bf16x8;
typedef __attribute__((ext_vector_type(4))) float f32x4;
typedef __attribute__((ext_vector_type(4))) unsigned int u32x4;

#define B_   8
#define C_   512
#define S_   1024
#define NH   8
#define C2_  1024
#define C3_  1536
#define QSCALE 0.1803368801111204f  // 0.125 * log2(e): softmax in exp2 domain

static __device__ __forceinline__ unsigned pack2(float a, float b) {
  unsigned short lo = __builtin_bit_cast(unsigned short, (bf16_t)a);
  unsigned short hi = __builtin_bit_cast(unsigned short, (bf16_t)b);
  return (unsigned)lo | ((unsigned)hi << 16);
}

static __device__ __forceinline__ void load_lds16(const void* g, void* l) {
  __builtin_amdgcn_global_load_lds(
      (const __attribute__((address_space(1))) unsigned*)g,
      (__attribute__((address_space(3))) unsigned*)l, 16, 0, 0);
}

// Stage ROUNDS*256 16B chunks into LDS (256-thread blocks). Rows are 128B
// (8 chunks); source chunk XOR-swizzled (c ^ row&7) so ds_read_b128 frags
// are conflict-free while the LDS dest stays linear (m173 pattern).
template<int ROUNDS>
static __device__ __forceinline__ void stage_swz(const bf16_t* g, int rstride,
                                                 char* lbuf, int tid) {
#pragma unroll
  for (int r = 0; r < ROUNDS; ++r) {
    int i = r * 256 + tid;
    int row = i >> 3;
    int cg = (i & 7) ^ (row & 7);
    load_lds16(g + (size_t)row * rstride + cg * 8,
               lbuf + r * 4096 + (tid & 192) * 16);  // wave-uniform base
  }
}

// 512-thread variant: one round covers 512 chunks = 64 rows = 8 KB.
static __device__ __forceinline__ void stage_swz512(const bf16_t* g, int rstride,
                                                    char* lbuf, int tid) {
  int row = tid >> 3;
  int cg = (tid & 7) ^ (row & 7);
  load_lds16(g + (size_t)row * rstride + cg * 8,
             lbuf + (tid & 448) * 16);  // wave-uniform base
}

// 512-thread, 4-round: stages a 256-row x 64-col bf16 tile (32 KB).
static __device__ __forceinline__ void stage_tile256(const bf16_t* g,
                                                     char* lbuf, int tid) {
#pragma unroll
  for (int r = 0; r < 4; ++r) {
    int i = r * 512 + tid;
    int row = i >> 3;
    int cg = (i & 7) ^ (row & 7);
    load_lds16(g + (size_t)row * C_ + cg * 8,
               lbuf + r * 8192 + (tid & 448) * 16);  // wave-uniform base
  }
}

// ---------------------------------------------------------------------------
// Merged prep: [0,256) GroupNorm+transpose, [256,1024) W_qkv prep,
// [1024,1280) W_out transpose.
// ---------------------------------------------------------------------------
__global__ __launch_bounds__(256) void prep_kernel(
    const float* __restrict__ x, const float* __restrict__ gsc,
    const float* __restrict__ gbi, const float* __restrict__ Wq,
    const float* __restrict__ bq, const float* __restrict__ Wo,
    bf16_t* __restrict__ h_t, bf16_t* __restrict__ wqkvp,
    bf16_t* __restrict__ woutt, float* __restrict__ bqp) {
  __shared__ __align__(16) char smem[65568];
  int bid = blockIdx.x;
  int tid = threadIdx.x;
  if (bid < 256) {
    // ---- GroupNorm + bf16 + transpose: x[b][c][s] -> h_t[b][s][c]
    float* xs = (float*)smem;
    float* red = (float*)(smem + 65536);
    int b = bid >> 5, g = bid & 31;
    const f32x4* xb4 = (const f32x4*)(x + ((size_t)b * C_ + g * 16) * S_);
    float s = 0.f, s2 = 0.f;
#pragma unroll
    for (int k = 0; k < 16; ++k) {
      int vf = k * 256 + tid;
      f32x4 v = xb4[vf];
      ((f32x4*)xs)[vf] = v;
#pragma unroll
      for (int e = 0; e < 4; ++e) { s += v[e]; s2 += v[e] * v[e]; }
    }
    for (int off = 32; off > 0; off >>= 1) {
      s  += __shfl_down(s, off);
      s2 += __shfl_down(s2, off);
    }
    int wave = tid >> 6, lane = tid & 63;
    if (lane == 0) { red[wave] = s; red[4 + wave] = s2; }
    __syncthreads();
    float ts = red[0] + red[1] + red[2] + red[3];
    float t2 = red[4] + red[5] + red[6] + red[7];
    const float inv_n = 1.f / (16.f * S_);
    float mean = ts * inv_n;
    float var  = t2 * inv_n - mean * mean;
    float rstd = rsqrtf(var + 1e-6f);
    float ac[16], bc[16];
#pragma unroll
    for (int cl = 0; cl < 16; ++cl) {
      float sc = gsc[g * 16 + cl] * rstd;
      ac[cl] = sc;
      bc[cl] = gbi[g * 16 + cl] - mean * sc;
    }
#pragma unroll
    for (int k = 0; k < 4; ++k) {
      int srow = tid + k * 256;
      unsigned ow[8];
#pragma unroll
      for (int p = 0; p < 8; ++p) {
        float y0 = xs[(2 * p    ) * 1024 + srow] * ac[2 * p    ] + bc[2 * p    ];
        float y1 = xs[(2 * p + 1) * 1024 + srow] * ac[2 * p + 1] + bc[2 * p + 1];
        ow[p] = pack2(y0, y1);
      }
      bf16_t* dst = h_t + ((size_t)b * S_ + srow) * C_ + g * 16;
      u32x4 v0, v1;
#pragma unroll
      for (int e = 0; e < 4; ++e) { v0[e] = ow[e]; v1[e] = ow[4 + e]; }
      *(u32x4*)dst = v0;
      *(u32x4*)(dst + 8) = v1;
    }
  } else if (bid < 1024) {
    // ---- W_qkv: transpose + permute d->d'=part*512+h*64+dq, fold QSCALE
    float* T = (float*)smem;
    int id = bid - 256;
    int d0 = (id % 48) * 32, c0 = (id / 48) * 32;
    int ld = tid & 31, lc = tid >> 5;
#pragma unroll
    for (int i = 0; i < 4; ++i) {
      int c = lc + i * 8;
      T[c * 33 + ld] = Wq[(size_t)(c0 + c) * C3_ + d0 + ld];
    }
    __syncthreads();
#pragma unroll
    for (int i = 0; i < 4; ++i) {
      int dd = lc + i * 8;
      int d = d0 + dd;
      int h = d / 192, rr = d - h * 192, part = rr >> 6, dq = rr & 63;
      float scl = (part == 0) ? QSCALE : 1.f;
      wqkvp[(size_t)(part * 512 + h * 64 + dq) * C_ + c0 + ld] =
          (bf16_t)(T[ld * 33 + dd] * scl);
    }
    if (id < 48 && tid < 32) {
      int d = d0 + tid;
      int h = d / 192, rr = d - h * 192, part = rr >> 6, dq = rr & 63;
      bqp[part * 512 + h * 64 + dq] = bq[d] * ((part == 0) ? QSCALE : 1.f);
    }
  } else {
    // ---- W_out transpose: Wo[512 c][512 d] f32 -> woutt[d][c] bf16
    float* T = (float*)smem;
    int id = bid - 1024;
    int c0 = (id & 15) * 32, r0 = (id >> 4) * 32;
    int lc = tid & 31, lr = tid >> 5;
#pragma unroll
    for (int i = 0; i < 4; ++i) {
      int r = lr + i * 8;
      T[r * 33 + lc] = Wo[(size_t)(r0 + r) * C_ + c0 + lc];
    }
    __syncthreads();
#pragma unroll
    for (int i = 0; i < 4; ++i) {
      int cc = lr + i * 8;
      woutt[(size_t)(c0 + cc) * C_ + r0 + lc] = (bf16_t)T[lc * 33 + cc];
    }
  }
}

// ---------------------------------------------------------------------------
// Templated staged-GEMM mainloop (256-thread, 128-wide tiles) for gemm_out.
// ---------------------------------------------------------------------------
template<int MF, int NF>
static __device__ __forceinline__ void gemm_loop(
    const bf16_t* Asrc, int Astride, const bf16_t* Bsrc, int Bstride,
    char* lds, int tid, f32x4 (&acc)[MF][NF]) {
  int wave = tid >> 6, lane = tid & 63;
  int wr = wave >> 1, wc = wave & 1;
  int lr = lane & 15, lq = lane >> 4;
  char* A0 = lds;
  char* B0 = lds + MF * 4096;
  char* A1 = lds + (MF + NF) * 4096;
  char* B1 = lds + (2 * MF + NF) * 4096;
  stage_swz<MF>(Asrc, Astride, A0, tid);
  stage_swz<NF>(Bsrc, Bstride, B0, tid);
#pragma unroll 1
  for (int ks = 0; ks < 8; ++ks) {
    if (ks < 7) {
      stage_swz<MF>(Asrc + (ks + 1) * 64, Astride, (ks & 1) ? A0 : A1, tid);
      stage_swz<NF>(Bsrc + (ks + 1) * 64, Bstride, (ks & 1) ? B0 : B1, tid);
      asm volatile("s_waitcnt vmcnt(%0)" :: "i"(MF + NF) : "memory");
    } else {
      asm volatile("s_waitcnt vmcnt(0)" ::: "memory");
    }
    __builtin_amdgcn_s_barrier();
    const char* Ab = (ks & 1) ? A1 : A0;
    const char* Bb = (ks & 1) ? B1 : B0;
#pragma unroll
    for (int kk = 0; kk < 2; ++kk) {
      int co = ((kk * 4 + lq) ^ (lr & 7)) << 4;
      bf16x8 a[MF], b[NF];
#pragma unroll
      for (int i = 0; i < MF; ++i)
        a[i] = *(const bf16x8*)(Ab + (wr * MF * 16 + i * 16 + lr) * 128 + co);
#pragma unroll
      for (int j = 0; j < NF; ++j)
        b[j] = *(const bf16x8*)(Bb + (wc * NF * 16 + j * 16 + lr) * 128 + co);
#pragma unroll
      for (int i = 0; i < MF; ++i)
#pragma unroll
        for (int j = 0; j < NF; ++j)
          acc[i][j] = __builtin_amdgcn_mfma_f32_16x16x32_bf16(a[i], b[j], acc[i][j], 0, 0, 0);
    }
    __builtin_amdgcn_s_barrier();
  }
}

// ---------------------------------------------------------------------------
// QKV projection, 256x256 tile, 8 waves (512 thr), 128 KB dynamic LDS.
// 192 blocks: bid<128 QK role (m=(b,s) tile bid&31, n=d' tile bid>>5);
// bid>=128 V role (swapped: m=dv' tile, n=(b,s) tile). XCD-grouped so all
// blocks touching one h panel land on one XCD.
// K-loop: BK=64, double-buffered, counted vmcnt(8) (loads span barriers),
// per-kk phase split, setprio around MFMA clusters. Epilogue bounces the
// 256x256 C tile through LDS for coalesced b128 stores.
// ---------------------------------------------------------------------------
__global__ __launch_bounds__(512, 2) void gemm_qkv_kernel(
    const bf16_t* __restrict__ h, const bf16_t* __restrict__ wq,
    const float* __restrict__ bias, bf16_t* __restrict__ qk,
    bf16_t* __restrict__ vt) {
  extern __shared__ __align__(16) char lds[];
  int tid = threadIdx.x;
  int bid = blockIdx.x;
  int wave = tid >> 6, lane = tid & 63;
  int wr = wave >> 2, wc = wave & 3;
  int lr = lane & 15, lq = lane >> 4;

  bool isV = bid >= 128;
  int m0, n0;
  const bf16_t *Asrc, *Bsrc;
  if (!isV) {
    m0 = (bid & 31) * 256; n0 = (bid >> 5) * 256;
    Asrc = h + (size_t)m0 * C_;
    Bsrc = wq + (size_t)n0 * C_;
  } else {
    int j2 = bid - 128;
    n0 = (j2 & 31) * 256; m0 = (j2 >> 5) * 256;
    Asrc = wq + (size_t)(1024 + m0) * C_;
    Bsrc = h + (size_t)n0 * C_;
  }
  char* A0 = lds;
  char* B0 = lds + 32768;
  char* A1 = lds + 65536;
  char* B1 = lds + 98304;

  f32x4 acc[8][4] = {};
  stage_tile256(Asrc + 0 * 64, A0, tid);
  stage_tile256(Bsrc + 0 * 64, B0, tid);
  stage_tile256(Asrc + 1 * 64, A1, tid);
  stage_tile256(Bsrc + 1 * 64, B1, tid);
#pragma unroll 1
  for (int kt = 0; kt < 8; ++kt) {
    if (kt <= 6) {
      asm volatile("s_waitcnt vmcnt(8)" ::: "memory");
    } else {
      asm volatile("s_waitcnt vmcnt(0)" ::: "memory");
    }
    __builtin_amdgcn_s_barrier();
    char* Abuf = (kt & 1) ? A1 : A0;
    char* Bbuf = (kt & 1) ? B1 : B0;
#pragma unroll
    for (int kk = 0; kk < 2; ++kk) {
      int co = ((kk * 4 + lq) ^ (lr & 7)) << 4;
      bf16x8 a[8], b[4];
#pragma unroll
      for (int i = 0; i < 8; ++i)
        a[i] = *(const bf16x8*)(Abuf + (wr * 128 + i * 16 + lr) * 128 + co);
#pragma unroll
      for (int j = 0; j < 4; ++j)
        b[j] = *(const bf16x8*)(Bbuf + (wc * 64 + j * 16 + lr) * 128 + co);
      __builtin_amdgcn_s_setprio(1);
#pragma unroll
      for (int i = 0; i < 8; ++i)
#pragma unroll
        for (int j = 0; j < 4; ++j)
          acc[i][j] = __builtin_amdgcn_mfma_f32_16x16x32_bf16(a[i], b[j], acc[i][j], 0, 0, 0);
      __builtin_amdgcn_s_setprio(0);
    }
    __builtin_amdgcn_s_barrier();
    if (kt < 6) {  // refill the buffer just consumed with tile kt+2
      stage_tile256(Asrc + (kt + 2) * 64, Abuf, tid);
      stage_tile256(Bsrc + (kt + 2) * 64, Bbuf, tid);
    }
  }
  __builtin_amdgcn_s_barrier();  // all LDS reads done before C-bounce

  unsigned short* tb = (unsigned short*)lds;
  if (!isV) {
    float bv[4];
#pragma unroll
    for (int j = 0; j < 4; ++j) bv[j] = bias[n0 + wc * 64 + j * 16 + lr];
#pragma unroll
    for (int i = 0; i < 8; ++i)
#pragma unroll
      for (int j = 0; j < 4; ++j)
#pragma unroll
        for (int r = 0; r < 4; ++r) {
          int row = wr * 128 + i * 16 + lq * 4 + r;
          int col = wc * 64 + j * 16 + lr;
          tb[row * 256 + col] =
              __builtin_bit_cast(unsigned short, (bf16_t)(acc[i][j][r] + bv[j]));
        }
    __builtin_amdgcn_s_barrier();
#pragma unroll
    for (int u = 0; u < 16; ++u) {
      int flat = u * 512 + tid;
      int row = flat >> 5, c = flat & 31;
      u32x4 v = *(const u32x4*)(tb + row * 256 + c * 8);
      int m = m0 + row, b = m >> 10, s = m & 1023;
      int d = n0 + c * 8;
      int hh = (d >> 6) & 7, det = ((d >> 9) << 6) + (d & 63);
      *(u32x4*)(qk + ((size_t)(b * S_ + s)) * C2_ + hh * 128 + det) = v;
    }
  } else {
    float bv[8][4];
#pragma unroll
    for (int i = 0; i < 8; ++i) {
      f32x4 t = *(const f32x4*)(bias + 1024 + m0 + wr * 128 + i * 16 + lq * 4);
#pragma unroll
      for (int r = 0; r < 4; ++r) bv[i][r] = t[r];
    }
#pragma unroll
    for (int i = 0; i < 8; ++i)
#pragma unroll
      for (int j = 0; j < 4; ++j)
#pragma unroll
        for (int r = 0; r < 4; ++r) {
          int row = wr * 128 + i * 16 + lq * 4 + r;
          int col = wc * 64 + j * 16 + lr;
          tb[row * 256 + col] =
              __builtin_bit_cast(unsigned short, (bf16_t)(acc[i][j][r] + bv[i][r]));
        }
    __builtin_amdgcn_s_barrier();
#pragma unroll
    for (int u = 0; u < 16; ++u) {
      int flat = u * 512 + tid;
      int row = flat >> 5, c = flat & 31;
      u32x4 v = *(const u32x4*)(tb + row * 256 + c * 8);
      int dvp = m0 + row;                 // h*64 + dv
      int hh = dvp >> 6, dv = dvp & 63;
      int n = n0 + c * 8, b = n >> 10, s = n & 1023;
      *(u32x4*)(vt + ((size_t)((b * NH + hh) * 64 + dv)) * S_ + s) = v;
    }
  }
}

// ---------------------------------------------------------------------------
// Flash attention. 256 blocks x 512 threads (8 waves x 32 q-rows).
// bid = qt*64 + (b*8+head). K/V LDS-staged (swizzled), 4 buffers, 2-deep
// prefetch (vmcnt(4)); swapped QK^T; exp2-domain softmax with defer-rescale;
// per-lane partial l; P via permlane32/16_swap; setprio around MFMA.
// ---------------------------------------------------------------------------
__global__ __launch_bounds__(512) void attn_kernel(
    const bf16_t* __restrict__ qk, const bf16_t* __restrict__ vt,
    bf16_t* __restrict__ ao) {
  __shared__ char lds[65536];
  int bid = blockIdx.x;
  int qt = bid >> 6, g = bid & 63;
  int b = g >> 3, head = g & 7;
  int tid = threadIdx.x, wave = tid >> 6, lane = tid & 63;
  int lr = lane & 15, lq = lane >> 4;
  int qb = qt * 256 + wave * 32;
  const bf16_t* qkb = qk + (size_t)b * S_ * C2_ + head * 128;
  const bf16_t* vtb = vt + (size_t)((b * NH + head) * 64) * S_;

  bf16x8 qf[2][2];
#pragma unroll
  for (int q2 = 0; q2 < 2; ++q2)
#pragma unroll
    for (int kk = 0; kk < 2; ++kk)
      qf[q2][kk] = *(const bf16x8*)(qkb + (size_t)(qb + q2 * 16 + lr) * C2_ + kk * 32 + lq * 8);

  f32x4 oacc[2][4] = {};
  float m_run[2] = {-1e30f, -1e30f}, l_run[2] = {0.f, 0.f};

  char* s0 = lds;
  char* s1 = lds + 16384;
  char* s2 = lds + 32768;
  char* s3 = lds + 49152;

#define STAGE_KV(kt, buf)                                                    \
  do {                                                                       \
    stage_swz512(qkb + (size_t)((kt) * 64) * C2_ + 64, C2_, (buf), tid);     \
    stage_swz512(vtb + (kt) * 64, S_, (buf) + 8192, tid);                    \
  } while (0)

  STAGE_KV(0, s0);
  STAGE_KV(1, s1);
#pragma unroll 1
  for (int kt = 0; kt < 16; ++kt) {
    if (kt < 14) {
      STAGE_KV(kt + 2, s2);
      asm volatile("s_waitcnt vmcnt(4)" ::: "memory");
    } else if (kt == 14) {
      asm volatile("s_waitcnt vmcnt(2)" ::: "memory");
    } else {
      asm volatile("s_waitcnt vmcnt(0)" ::: "memory");
    }
    __builtin_amdgcn_s_barrier();

    // S^T = K Q^T  (Q pre-scaled by 0.125*log2e)
    f32x4 sacc[2][4] = {};
    __builtin_amdgcn_s_setprio(1);
#pragma unroll
    for (int kk = 0; kk < 2; ++kk) {
      int co = ((kk * 4 + lq) ^ (lr & 7)) << 4;
      bf16x8 kf[4];
#pragma unroll
      for (int mf = 0; mf < 4; ++mf)
        kf[mf] = *(const bf16x8*)(s0 + (mf * 16 + lr) * 128 + co);
#pragma unroll
      for (int q2 = 0; q2 < 2; ++q2)
#pragma unroll
        for (int mf = 0; mf < 4; ++mf)
          sacc[q2][mf] = __builtin_amdgcn_mfma_f32_16x16x32_bf16(kf[mf], qf[q2][kk], sacc[q2][mf], 0, 0, 0);
    }
    __builtin_amdgcn_s_setprio(0);

    // online softmax; lane owns q-col (q2,lr), 16 local t-values each
    float mx[2];
#pragma unroll
    for (int q2 = 0; q2 < 2; ++q2) {
      float m = -1e30f;
#pragma unroll
      for (int mf = 0; mf < 4; ++mf)
#pragma unroll
        for (int r = 0; r < 4; ++r) m = fmaxf(m, sacc[q2][mf][r]);
      m = fmaxf(m, __shfl_xor(m, 16));
      m = fmaxf(m, __shfl_xor(m, 32));
      mx[q2] = m;
    }
    if (__any(fmaxf(mx[0] - m_run[0], mx[1] - m_run[1]) > 11.f)) {  // T13
#pragma unroll
      for (int q2 = 0; q2 < 2; ++q2) {
        float mn = fmaxf(m_run[q2], mx[q2]);
        float alpha = __builtin_amdgcn_exp2f(m_run[q2] - mn);
        m_run[q2] = mn;
        l_run[q2] *= alpha;
#pragma unroll
        for (int df = 0; df < 4; ++df)
#pragma unroll
          for (int r = 0; r < 4; ++r) oacc[q2][df][r] *= alpha;
      }
    }
    unsigned pk[2][4][2];
#pragma unroll
    for (int q2 = 0; q2 < 2; ++q2) {
      float p[4][4];
      float rs = 0.f;
#pragma unroll
      for (int mf = 0; mf < 4; ++mf)
#pragma unroll
        for (int r = 0; r < 4; ++r) {
          float v = __builtin_amdgcn_exp2f(sacc[q2][mf][r] - m_run[q2]);
          p[mf][r] = v; rs += v;
        }
      l_run[q2] += rs;                     // per-lane partial; reduced at end
#pragma unroll
      for (int mf = 0; mf < 4; ++mf)
#pragma unroll
        for (int j = 0; j < 2; ++j)
          pk[q2][mf][j] = pack2(p[mf][2 * j], p[mf][2 * j + 1]);
    }

    // O^T += V^T P^T ; P B-frags via permlane32+permlane16 swaps
#pragma unroll
    for (int kk = 0; kk < 2; ++kk) {
      int co = ((kk * 4 + lq) ^ (lr & 7)) << 4;
      bf16x8 vf[4];
#pragma unroll
      for (int df = 0; df < 4; ++df)
        vf[df] = *(const bf16x8*)(s0 + 8192 + (df * 16 + lr) * 128 + co);
#pragma unroll
      for (int q2 = 0; q2 < 2; ++q2) {
        unsigned w0 = pk[q2][2 * kk + 0][0], w2 = pk[q2][2 * kk + 1][0];
        unsigned w1 = pk[q2][2 * kk + 0][1], w3 = pk[q2][2 * kk + 1][1];
        asm("v_permlane32_swap_b32 %0, %1" : "+v"(w0), "+v"(w2));
        asm("v_permlane16_swap_b32 %0, %1" : "+v"(w0), "+v"(w2));
        asm("v_permlane32_swap_b32 %0, %1" : "+v"(w1), "+v"(w3));
        asm("v_permlane16_swap_b32 %0, %1" : "+v"(w1), "+v"(w3));
        u32x4 bw; bw[0] = w0; bw[1] = w1; bw[2] = w2; bw[3] = w3;
        bf16x8 pb = __builtin_bit_cast(bf16x8, bw);
        __builtin_amdgcn_s_setprio(1);
#pragma unroll
        for (int df = 0; df < 4; ++df)
          oacc[q2][df] = __builtin_amdgcn_mfma_f32_16x16x32_bf16(vf[df], pb, oacc[q2][df], 0, 0, 0);
        __builtin_amdgcn_s_setprio(0);
      }
    }
    char* tp = s0; s0 = s1; s1 = s2; s2 = s3; s3 = tp;
  }

  // epilogue: reduce per-lane l partials, write O^T
#pragma unroll
  for (int q2 = 0; q2 < 2; ++q2) {
    float lt = l_run[q2];
    lt += __shfl_xor(lt, 16);
    lt += __shfl_xor(lt, 32);
    float inv = 1.f / lt;
    bf16_t* aop = ao + ((size_t)b * S_ + qb + q2 * 16 + lr) * C_ + head * 64;
#pragma unroll
    for (int df = 0; df < 4; ++df)
#pragma unroll
      for (int rp = 0; rp < 4; rp += 2) {
        unsigned u = pack2(oacc[q2][df][rp] * inv, oacc[q2][df][rp + 1] * inv);
        *(unsigned*)(aop + df * 16 + lq * 4 + rp) = u;
      }
  }
#undef STAGE_KV
}

// ---------------------------------------------------------------------------
// Out projection + bias + residual: out[b][d][s] = x + b_out[d] + ao @ W_out
// 512 blocks, 64m x 128n tiles; bid = n*128 + m (same-ao-panel -> same XCD).
// ---------------------------------------------------------------------------
__global__ __launch_bounds__(256) void gemm_out_kernel(
    const bf16_t* __restrict__ A, const bf16_t* __restrict__ Bw,
    const float* __restrict__ bias, const float* __restrict__ xres,
    float* __restrict__ out) {
  __shared__ char lds[49152];
  int tid = threadIdx.x;
  int bid = blockIdx.x;
  int m0 = (bid & 127) * 64, n0 = (bid >> 7) * 128;
  f32x4 acc[2][4] = {};
  gemm_loop<2, 4>(A + (size_t)m0 * C_, C_, Bw + (size_t)n0 * C_, C_, lds, tid, acc);
  int wave = tid >> 6, lane = tid & 63;
  int wr = wave >> 1, wc = wave & 1, lr = lane & 15, lq = lane >> 4;
#pragma unroll
  for (int i = 0; i < 2; ++i) {
#pragma unroll
    for (int j = 0; j < 4; ++j) {
      int d = n0 + wc * 64 + j * 16 + lr;
      int m = m0 + wr * 32 + i * 16 + lq * 4;
      int b = m >> 10, s = m & 1023;
      size_t o = ((size_t)b * C_ + d) * S_ + s;
      f32x4 res = *(const f32x4*)(xres + o);
      f32x4 val;
      float bd = bias[d];
#pragma unroll
      for (int r = 0; r < 4; ++r) val[r] = res[r] + bd + acc[i][j][r];
      *(f32x4*)(out + o) = val;
    }
  }
}

// ---------------------------------------------------------------------------
extern "C" void kernel_launch(void* const* d_in, const int* in_sizes, int n_in,
                              void* d_out, int out_size, void* d_ws, size_t ws_size,
                              hipStream_t stream) {
  const float* x        = (const float*)d_in[0];
  const float* gn_scale = (const float*)d_in[1];
  const float* gn_bias  = (const float*)d_in[2];
  const float* W_qkv    = (const float*)d_in[3];
  const float* b_qkv    = (const float*)d_in[4];
  const float* W_out    = (const float*)d_in[5];
  const float* b_out    = (const float*)d_in[6];
  float* out = (float*)d_out;

  char* ws = (char*)d_ws;
  bf16_t* h_t   = (bf16_t*)(ws);               // 8 MiB  [b][s][c]
  bf16_t* qk_t  = (bf16_t*)(ws + 8388608);     // 16 MiB [b][s][h*128+det]
  bf16_t* vt    = (bf16_t*)(ws + 25165824);    // 8 MiB  [b][h][dv][s]
  bf16_t* ao_t  = (bf16_t*)(ws + 33554432);    // 8 MiB  [b][s][c]
  bf16_t* wqkvp = (bf16_t*)(ws + 41943040);    // 1.5 MiB [d'][c] permuted
  bf16_t* woutt = (bf16_t*)(ws + 43515904);    // 0.5 MiB [d][c]
  float* bqp = (float*)d_out;  // 1536 f32 bias, overwritten later by gemm_out

  hipFuncSetAttribute((const void*)gemm_qkv_kernel,
                      hipFuncAttributeMaxDynamicSharedMemorySize, 131072);

  prep_kernel<<<1280, 256, 0, stream>>>(x, gn_scale, gn_bias, W_qkv, b_qkv,
                                        W_out, h_t, wqkvp, woutt, bqp);
  gemm_qkv_kernel<<<192, 512, 131072, stream>>>(h_t, wqkvp, bqp, qk_t, vt);
  attn_kernel<<<256, 512, 0, stream>>>(qk_t, vt, ao_t);
  gemm_out_kernel<<<512, 256, 0, stream>>>(ao_t, woutt, b_out, x, out);
}

// Round 8
// 77.260 us; speedup vs baseline: 1.0040x; 1.0040x over previous
//
#include <hip/hip_runtime.h>
#include <hip/hip_bf16.h>

typedef __bf16 bf16_t;
typedef __attribute__((ext_vector_type(8))) __bf16 bf16x8;
typedef __attribute__((ext_vector_type(4))) float f32x4;
typedef __attribute__((ext_vector_type(4))) unsigned int u32x4;

#define B_   8
#define C_   512
#define S_   1024
#define NH   8
#define C2_  1024
#define C3_  1536
#define QSCALE 0.1803368801111204f  // 0.125 * log2(e): softmax in exp2 domain

static __device__ __forceinline__ unsigned pack2(float a, float b) {
  unsigned short lo = __builtin_bit_cast(unsigned short, (bf16_t)a);
  unsigned short hi = __builtin_bit_cast(unsigned short, (bf16_t)b);
  return (unsigned)lo | ((unsigned)hi << 16);
}

static __device__ __forceinline__ void load_lds16(const void* g, void* l) {
  __builtin_amdgcn_global_load_lds(
      (const __attribute__((address_space(1))) unsigned*)g,
      (__attribute__((address_space(3))) unsigned*)l, 16, 0, 0);
}

// Stage ROUNDS*256 16B chunks into LDS (256-thread blocks). Rows are 128B
// (8 chunks); source chunk XOR-swizzled (c ^ row&7) so ds_read_b128 frags
// are conflict-free while the LDS dest stays linear (m173 pattern).
template<int ROUNDS>
static __device__ __forceinline__ void stage_swz(const bf16_t* g, int rstride,
                                                 char* lbuf, int tid) {
#pragma unroll
  for (int r = 0; r < ROUNDS; ++r) {
    int i = r * 256 + tid;
    int row = i >> 3;
    int cg = (i & 7) ^ (row & 7);
    load_lds16(g + (size_t)row * rstride + cg * 8,
               lbuf + r * 4096 + (tid & 192) * 16);  // wave-uniform base
  }
}

// ---------------------------------------------------------------------------
// Merged prep: [0,256) GroupNorm+transpose, [256,1024) W_qkv prep,
// [1024,1280) W_out transpose.
// ---------------------------------------------------------------------------
__global__ __launch_bounds__(256) void prep_kernel(
    const float* __restrict__ x, const float* __restrict__ gsc,
    const float* __restrict__ gbi, const float* __restrict__ Wq,
    const float* __restrict__ bq, const float* __restrict__ Wo,
    bf16_t* __restrict__ h_t, bf16_t* __restrict__ wqkvp,
    bf16_t* __restrict__ woutt, float* __restrict__ bqp) {
  __shared__ __align__(16) char smem[65568];
  int bid = blockIdx.x;
  int tid = threadIdx.x;
  if (bid < 256) {
    // ---- GroupNorm + bf16 + transpose: x[b][c][s] -> h_t[b][s][c]
    float* xs = (float*)smem;
    float* red = (float*)(smem + 65536);
    int b = bid >> 5, g = bid & 31;
    const f32x4* xb4 = (const f32x4*)(x + ((size_t)b * C_ + g * 16) * S_);
    float s = 0.f, s2 = 0.f;
#pragma unroll
    for (int k = 0; k < 16; ++k) {
      int vf = k * 256 + tid;
      f32x4 v = xb4[vf];
      ((f32x4*)xs)[vf] = v;
#pragma unroll
      for (int e = 0; e < 4; ++e) { s += v[e]; s2 += v[e] * v[e]; }
    }
    for (int off = 32; off > 0; off >>= 1) {
      s  += __shfl_down(s, off);
      s2 += __shfl_down(s2, off);
    }
    int wave = tid >> 6, lane = tid & 63;
    if (lane == 0) { red[wave] = s; red[4 + wave] = s2; }
    __syncthreads();
    float ts = red[0] + red[1] + red[2] + red[3];
    float t2 = red[4] + red[5] + red[6] + red[7];
    const float inv_n = 1.f / (16.f * S_);
    float mean = ts * inv_n;
    float var  = t2 * inv_n - mean * mean;
    float rstd = rsqrtf(var + 1e-6f);
    float ac[16], bc[16];
#pragma unroll
    for (int cl = 0; cl < 16; ++cl) {
      float sc = gsc[g * 16 + cl] * rstd;
      ac[cl] = sc;
      bc[cl] = gbi[g * 16 + cl] - mean * sc;
    }
#pragma unroll
    for (int k = 0; k < 4; ++k) {
      int srow = tid + k * 256;
      unsigned ow[8];
#pragma unroll
      for (int p = 0; p < 8; ++p) {
        float y0 = xs[(2 * p    ) * 1024 + srow] * ac[2 * p    ] + bc[2 * p    ];
        float y1 = xs[(2 * p + 1) * 1024 + srow] * ac[2 * p + 1] + bc[2 * p + 1];
        ow[p] = pack2(y0, y1);
      }
      bf16_t* dst = h_t + ((size_t)b * S_ + srow) * C_ + g * 16;
      u32x4 v0, v1;
#pragma unroll
      for (int e = 0; e < 4; ++e) { v0[e] = ow[e]; v1[e] = ow[4 + e]; }
      *(u32x4*)dst = v0;
      *(u32x4*)(dst + 8) = v1;
    }
  } else if (bid < 1024) {
    // ---- W_qkv: transpose + permute d->d'=part*512+h*64+dq, fold QSCALE
    float* T = (float*)smem;
    int id = bid - 256;
    int d0 = (id % 48) * 32, c0 = (id / 48) * 32;
    int ld = tid & 31, lc = tid >> 5;
#pragma unroll
    for (int i = 0; i < 4; ++i) {
      int c = lc + i * 8;
      T[c * 33 + ld] = Wq[(size_t)(c0 + c) * C3_ + d0 + ld];
    }
    __syncthreads();
#pragma unroll
    for (int i = 0; i < 4; ++i) {
      int dd = lc + i * 8;
      int d = d0 + dd;
      int h = d / 192, rr = d - h * 192, part = rr >> 6, dq = rr & 63;
      float scl = (part == 0) ? QSCALE : 1.f;
      wqkvp[(size_t)(part * 512 + h * 64 + dq) * C_ + c0 + ld] =
          (bf16_t)(T[ld * 33 + dd] * scl);
    }
    if (id < 48 && tid < 32) {
      int d = d0 + tid;
      int h = d / 192, rr = d - h * 192, part = rr >> 6, dq = rr & 63;
      bqp[part * 512 + h * 64 + dq] = bq[d] * ((part == 0) ? QSCALE : 1.f);
    }
  } else {
    // ---- W_out transpose: Wo[512 c][512 d] f32 -> woutt[d][c] bf16
    float* T = (float*)smem;
    int id = bid - 1024;
    int c0 = (id & 15) * 32, r0 = (id >> 4) * 32;
    int lc = tid & 31, lr = tid >> 5;
#pragma unroll
    for (int i = 0; i < 4; ++i) {
      int r = lr + i * 8;
      T[r * 33 + lc] = Wo[(size_t)(r0 + r) * C_ + c0 + lc];
    }
    __syncthreads();
#pragma unroll
    for (int i = 0; i < 4; ++i) {
      int cc = lr + i * 8;
      woutt[(size_t)(c0 + cc) * C_ + r0 + lc] = (bf16_t)T[lc * 33 + cc];
    }
  }
}

// ---------------------------------------------------------------------------
// Templated staged-GEMM mainloop: C[MF*32 m][NF*32 n] = A[m][k]*B[n][k], K=512.
// BK=64, double-buffered global_load_lds staging, counted vmcnt, raw barriers.
// 256 threads as 2x2 waves; per wave MF x NF 16x16 frags.
// ---------------------------------------------------------------------------
template<int MF, int NF>
static __device__ __forceinline__ void gemm_loop(
    const bf16_t* Asrc, int Astride, const bf16_t* Bsrc, int Bstride,
    char* lds, int tid, f32x4 (&acc)[MF][NF]) {
  int wave = tid >> 6, lane = tid & 63;
  int wr = wave >> 1, wc = wave & 1;
  int lr = lane & 15, lq = lane >> 4;
  char* A0 = lds;
  char* B0 = lds + MF * 4096;
  char* A1 = lds + (MF + NF) * 4096;
  char* B1 = lds + (2 * MF + NF) * 4096;
  stage_swz<MF>(Asrc, Astride, A0, tid);
  stage_swz<NF>(Bsrc, Bstride, B0, tid);
#pragma unroll 1
  for (int ks = 0; ks < 8; ++ks) {
    if (ks < 7) {
      stage_swz<MF>(Asrc + (ks + 1) * 64, Astride, (ks & 1) ? A0 : A1, tid);
      stage_swz<NF>(Bsrc + (ks + 1) * 64, Bstride, (ks & 1) ? B0 : B1, tid);
      asm volatile("s_waitcnt vmcnt(%0)" :: "i"(MF + NF) : "memory");
    } else {
      asm volatile("s_waitcnt vmcnt(0)" ::: "memory");
    }
    __builtin_amdgcn_s_barrier();
    const char* Ab = (ks & 1) ? A1 : A0;
    const char* Bb = (ks & 1) ? B1 : B0;
#pragma unroll
    for (int kk = 0; kk < 2; ++kk) {
      int co = ((kk * 4 + lq) ^ (lr & 7)) << 4;
      bf16x8 a[MF], b[NF];
#pragma unroll
      for (int i = 0; i < MF; ++i)
        a[i] = *(const bf16x8*)(Ab + (wr * MF * 16 + i * 16 + lr) * 128 + co);
#pragma unroll
      for (int j = 0; j < NF; ++j)
        b[j] = *(const bf16x8*)(Bb + (wc * NF * 16 + j * 16 + lr) * 128 + co);
#pragma unroll
      for (int i = 0; i < MF; ++i)
#pragma unroll
        for (int j = 0; j < NF; ++j)
          acc[i][j] = __builtin_amdgcn_mfma_f32_16x16x32_bf16(a[i], b[j], acc[i][j], 0, 0, 0);
    }
    __builtin_amdgcn_s_barrier();
  }
}

// ---------------------------------------------------------------------------
// Merged QKV projection. 1-D grid, 768 blocks, XCD-grouped (same h_t panel
// -> same XCD). bid<512: QK role -> qk[b][s][h*128+det]; else V role
// (swapped operands) -> vt[b][h][dv][s].
// ---------------------------------------------------------------------------
__global__ __launch_bounds__(256) void gemm_qkv_kernel(
    const bf16_t* __restrict__ h, const bf16_t* __restrict__ wq,
    const float* __restrict__ bias, bf16_t* __restrict__ qk,
    bf16_t* __restrict__ vt) {
  __shared__ char lds[65536];
  int tid = threadIdx.x;
  int bid = blockIdx.x;
  int wave = tid >> 6, lane = tid & 63;
  int wr = wave >> 1, wc = wave & 1, lr = lane & 15, lq = lane >> 4;
  unsigned short* tb = (unsigned short*)lds;
  if (bid < 512) {
    int m0 = (bid & 63) * 128, n0 = (bid >> 6) * 128;
    f32x4 acc[4][4] = {};
    gemm_loop<4, 4>(h + (size_t)m0 * C_, C_, wq + (size_t)n0 * C_, C_, lds, tid, acc);
    float bv[4];
#pragma unroll
    for (int j = 0; j < 4; ++j) bv[j] = bias[n0 + wc * 64 + j * 16 + lr];
#pragma unroll
    for (int i = 0; i < 4; ++i)
#pragma unroll
      for (int j = 0; j < 4; ++j)
#pragma unroll
        for (int r = 0; r < 4; ++r) {
          int row = wr * 64 + i * 16 + lq * 4 + r;
          int col = wc * 64 + j * 16 + lr;
          int byte = row * 256 + (((col >> 3) ^ (row & 7)) << 4) + ((col & 7) << 1);
          tb[byte >> 1] = __builtin_bit_cast(unsigned short, (bf16_t)(acc[i][j][r] + bv[j]));
        }
    __builtin_amdgcn_s_barrier();
#pragma unroll
    for (int u = 0; u < 8; ++u) {
      int flat = tid + u * 256;
      int row = flat >> 4, c = flat & 15;
      u32x4 v = *(const u32x4*)(lds + row * 256 + ((c ^ (row & 7)) << 4));
      int m = m0 + row, b = m >> 10, s = m & 1023;
      int d = n0 + c * 8;
      int hh = (d >> 6) & 7, det = ((d >> 9) << 6) + (d & 63);
      *(u32x4*)(qk + ((size_t)(b * S_ + s)) * C2_ + hh * 128 + det) = v;
    }
  } else {
    int j2 = bid - 512;
    int n0 = (j2 & 63) * 128, m0 = (j2 >> 6) * 128;
    f32x4 acc[4][4] = {};
    gemm_loop<4, 4>(wq + (size_t)(1024 + m0) * C_, C_, h + (size_t)n0 * C_, C_, lds, tid, acc);
    float bv[4][4];
#pragma unroll
    for (int i = 0; i < 4; ++i) {
      f32x4 t = *(const f32x4*)(bias + 1024 + m0 + wr * 64 + i * 16 + lq * 4);
#pragma unroll
      for (int r = 0; r < 4; ++r) bv[i][r] = t[r];
    }
#pragma unroll
    for (int i = 0; i < 4; ++i)
#pragma unroll
      for (int j = 0; j < 4; ++j)
#pragma unroll
        for (int r = 0; r < 4; ++r) {
          int row = wr * 64 + i * 16 + lq * 4 + r;
          int col = wc * 64 + j * 16 + lr;
          int byte = row * 256 + (((col >> 3) ^ (row & 7)) << 4) + ((col & 7) << 1);
          tb[byte >> 1] = __builtin_bit_cast(unsigned short, (bf16_t)(acc[i][j][r] + bv[i][r]));
        }
    __builtin_amdgcn_s_barrier();
#pragma unroll
    for (int u = 0; u < 8; ++u) {
      int flat = tid + u * 256;
      int row = flat >> 4, c = flat & 15;
      u32x4 v = *(const u32x4*)(lds + row * 256 + ((c ^ (row & 7)) << 4));
      int m = m0 + row;  // h*64+dv
      int hh = m >> 6, dv = m & 63;
      int n = n0 + c * 8, b = n >> 10, s = n & 1023;
      *(u32x4*)(vt + ((size_t)((b * NH + hh) * 64 + dv)) * S_ + s) = v;
    }
  }
}

// ---------------------------------------------------------------------------
// Flash attention. 256 blocks x 512 threads (8 waves x 32 q-rows).
// KBLK=128: 8 K-tiles, 3 LDS buffers (96KB dynamic), stage-distance-2 with
// counted vmcnt(4) (no mid-loop drain), ONE barrier per tile, 64 MFMA/wave
// per barrier. Swapped QK^T; exp2-domain softmax with defer-rescale;
// per-lane partial l; P via permlane32/16_swap; setprio around MFMA.
// K tile: 128 t-rows x 64 d (128B rows, 8-chunk XOR swizzle).
// V tile: 64 dv-rows x 128 t (256B rows, 16-chunk XOR swizzle).
// ---------------------------------------------------------------------------
__global__ __launch_bounds__(512, 2) void attn_kernel(
    const bf16_t* __restrict__ qk, const bf16_t* __restrict__ vt,
    bf16_t* __restrict__ ao) {
  extern __shared__ __align__(16) char alds[];
  int bid = blockIdx.x;
  int qt = bid >> 6, g = bid & 63;
  int b = g >> 3, head = g & 7;
  int tid = threadIdx.x, wave = tid >> 6, lane = tid & 63;
  int lr = lane & 15, lq = lane >> 4;
  int qb = qt * 256 + wave * 32;
  const bf16_t* qkb = qk + (size_t)b * S_ * C2_ + head * 128;
  const bf16_t* vtb = vt + (size_t)((b * NH + head) * 64) * S_;

  bf16x8 qf[2][2];
#pragma unroll
  for (int q2 = 0; q2 < 2; ++q2)
#pragma unroll
    for (int kk = 0; kk < 2; ++kk)
      qf[q2][kk] = *(const bf16x8*)(qkb + (size_t)(qb + q2 * 16 + lr) * C2_ + kk * 32 + lq * 8);

  f32x4 oacc[2][4] = {};
  float m_run[2] = {-1e30f, -1e30f}, l_run[2] = {0.f, 0.f};

  char* s0 = alds;
  char* s1 = alds + 32768;
  char* s2 = alds + 65536;

#define STAGE_KV(kt, buf)                                                    \
  do {                                                                       \
    _Pragma("unroll")                                                        \
    for (int rr_ = 0; rr_ < 2; ++rr_) {                                      \
      int i_ = rr_ * 512 + tid;                                              \
      int row_ = i_ >> 3;                                                    \
      int cg_ = (i_ & 7) ^ (row_ & 7);                                       \
      load_lds16(qkb + (size_t)((kt) * 128 + row_) * C2_ + 64 + cg_ * 8,     \
                 (buf) + rr_ * 8192 + (tid & 448) * 16);                     \
    }                                                                        \
    _Pragma("unroll")                                                        \
    for (int rr_ = 0; rr_ < 2; ++rr_) {                                      \
      int i_ = rr_ * 512 + tid;                                              \
      int row_ = i_ >> 4;                                                    \
      int cg_ = (i_ & 15) ^ (row_ & 15);                                     \
      load_lds16(vtb + (size_t)row_ * S_ + (kt) * 128 + cg_ * 8,             \
                 (buf) + 16384 + rr_ * 8192 + (tid & 448) * 16);             \
    }                                                                        \
  } while (0)

  STAGE_KV(0, s0);
  STAGE_KV(1, s1);
#pragma unroll 1
  for (int kt = 0; kt < 8; ++kt) {
    if (kt < 7) {
      asm volatile("s_waitcnt vmcnt(4)" ::: "memory");
    } else {
      asm volatile("s_waitcnt vmcnt(0)" ::: "memory");
    }
    __builtin_amdgcn_s_barrier();
    if (kt < 6) STAGE_KV(kt + 2, s2);   // s2: last read at kt-1, safe

    // S^T = K Q^T  (Q pre-scaled by 0.125*log2e); 128 t-rows
    f32x4 sacc[2][8] = {};
    __builtin_amdgcn_s_setprio(1);
#pragma unroll
    for (int kk = 0; kk < 2; ++kk) {
      int co = ((kk * 4 + lq) ^ (lr & 7)) << 4;
#pragma unroll
      for (int mf = 0; mf < 8; ++mf) {
        bf16x8 kf = *(const bf16x8*)(s0 + (mf * 16 + lr) * 128 + co);
#pragma unroll
        for (int q2 = 0; q2 < 2; ++q2)
          sacc[q2][mf] = __builtin_amdgcn_mfma_f32_16x16x32_bf16(kf, qf[q2][kk], sacc[q2][mf], 0, 0, 0);
      }
    }
    __builtin_amdgcn_s_setprio(0);

    // online softmax; lane owns q-col (q2,lr), 32 local t-values each
    float mx[2];
#pragma unroll
    for (int q2 = 0; q2 < 2; ++q2) {
      float m = -1e30f;
#pragma unroll
      for (int mf = 0; mf < 8; ++mf)
#pragma unroll
        for (int r = 0; r < 4; ++r) m = fmaxf(m, sacc[q2][mf][r]);
      m = fmaxf(m, __shfl_xor(m, 16));
      m = fmaxf(m, __shfl_xor(m, 32));
      mx[q2] = m;
    }
    if (__any(fmaxf(mx[0] - m_run[0], mx[1] - m_run[1]) > 11.f)) {  // T13
#pragma unroll
      for (int q2 = 0; q2 < 2; ++q2) {
        float mn = fmaxf(m_run[q2], mx[q2]);
        float alpha = __builtin_amdgcn_exp2f(m_run[q2] - mn);
        m_run[q2] = mn;
        l_run[q2] *= alpha;
#pragma unroll
        for (int df = 0; df < 4; ++df)
#pragma unroll
          for (int r = 0; r < 4; ++r) oacc[q2][df][r] *= alpha;
      }
    }
    unsigned pk[2][8][2];
#pragma unroll
    for (int q2 = 0; q2 < 2; ++q2) {
      float rs = 0.f;
#pragma unroll
      for (int mf = 0; mf < 8; ++mf) {
        float p0 = __builtin_amdgcn_exp2f(sacc[q2][mf][0] - m_run[q2]);
        float p1 = __builtin_amdgcn_exp2f(sacc[q2][mf][1] - m_run[q2]);
        float p2 = __builtin_amdgcn_exp2f(sacc[q2][mf][2] - m_run[q2]);
        float p3 = __builtin_amdgcn_exp2f(sacc[q2][mf][3] - m_run[q2]);
        rs += (p0 + p1) + (p2 + p3);
        pk[q2][mf][0] = pack2(p0, p1);
        pk[q2][mf][1] = pack2(p2, p3);
      }
      l_run[q2] += rs;                     // per-lane partial; reduced at end
    }

    // O^T += V^T P^T ; P B-frags via permlane32+permlane16 swaps
#pragma unroll
    for (int kp = 0; kp < 4; ++kp) {
      int cov = ((kp * 4 + lq) ^ lr) << 4;
      bf16x8 vf[4];
#pragma unroll
      for (int df = 0; df < 4; ++df)
        vf[df] = *(const bf16x8*)(s0 + 16384 + (df * 16 + lr) * 256 + cov);
#pragma unroll
      for (int q2 = 0; q2 < 2; ++q2) {
        unsigned w0 = pk[q2][2 * kp + 0][0], w2 = pk[q2][2 * kp + 1][0];
        unsigned w1 = pk[q2][2 * kp + 0][1], w3 = pk[q2][2 * kp + 1][1];
        asm("v_permlane32_swap_b32 %0, %1" : "+v"(w0), "+v"(w2));
        asm("v_permlane16_swap_b32 %0, %1" : "+v"(w0), "+v"(w2));
        asm("v_permlane32_swap_b32 %0, %1" : "+v"(w1), "+v"(w3));
        asm("v_permlane16_swap_b32 %0, %1" : "+v"(w1), "+v"(w3));
        u32x4 bw; bw[0] = w0; bw[1] = w1; bw[2] = w2; bw[3] = w3;
        bf16x8 pb = __builtin_bit_cast(bf16x8, bw);
        __builtin_amdgcn_s_setprio(1);
#pragma unroll
        for (int df = 0; df < 4; ++df)
          oacc[q2][df] = __builtin_amdgcn_mfma_f32_16x16x32_bf16(vf[df], pb, oacc[q2][df], 0, 0, 0);
        __builtin_amdgcn_s_setprio(0);
      }
    }
    char* tp = s0; s0 = s1; s1 = s2; s2 = tp;
  }

  // epilogue: reduce per-lane l partials, write O^T
#pragma unroll
  for (int q2 = 0; q2 < 2; ++q2) {
    float lt = l_run[q2];
    lt += __shfl_xor(lt, 16);
    lt += __shfl_xor(lt, 32);
    float inv = 1.f / lt;
    bf16_t* aop = ao + ((size_t)b * S_ + qb + q2 * 16 + lr) * C_ + head * 64;
#pragma unroll
    for (int df = 0; df < 4; ++df)
#pragma unroll
      for (int rp = 0; rp < 4; rp += 2) {
        unsigned u = pack2(oacc[q2][df][rp] * inv, oacc[q2][df][rp + 1] * inv);
        *(unsigned*)(aop + df * 16 + lq * 4 + rp) = u;
      }
  }
#undef STAGE_KV
}

// ---------------------------------------------------------------------------
// Out projection + bias + residual: out[b][d][s] = x + b_out[d] + ao @ W_out
// 512 blocks, 64m x 128n tiles; bid = n*128 + m (same-ao-panel -> same XCD).
// ---------------------------------------------------------------------------
__global__ __launch_bounds__(256) void gemm_out_kernel(
    const bf16_t* __restrict__ A, const bf16_t* __restrict__ Bw,
    const float* __restrict__ bias, const float* __restrict__ xres,
    float* __restrict__ out) {
  __shared__ char lds[49152];
  int tid = threadIdx.x;
  int bid = blockIdx.x;
  int m0 = (bid & 127) * 64, n0 = (bid >> 7) * 128;
  f32x4 acc[2][4] = {};
  gemm_loop<2, 4>(A + (size_t)m0 * C_, C_, Bw + (size_t)n0 * C_, C_, lds, tid, acc);
  int wave = tid >> 6, lane = tid & 63;
  int wr = wave >> 1, wc = wave & 1, lr = lane & 15, lq = lane >> 4;
#pragma unroll
  for (int i = 0; i < 2; ++i) {
#pragma unroll
    for (int j = 0; j < 4; ++j) {
      int d = n0 + wc * 64 + j * 16 + lr;
      int m = m0 + wr * 32 + i * 16 + lq * 4;
      int b = m >> 10, s = m & 1023;
      size_t o = ((size_t)b * C_ + d) * S_ + s;
      f32x4 res = *(const f32x4*)(xres + o);
      f32x4 val;
      float bd = bias[d];
#pragma unroll
      for (int r = 0; r < 4; ++r) val[r] = res[r] + bd + acc[i][j][r];
      *(f32x4*)(out + o) = val;
    }
  }
}

// ---------------------------------------------------------------------------
extern "C" void kernel_launch(void* const* d_in, const int* in_sizes, int n_in,
                              void* d_out, int out_size, void* d_ws, size_t ws_size,
                              hipStream_t stream) {
  const float* x        = (const float*)d_in[0];
  const float* gn_scale = (const float*)d_in[1];
  const float* gn_bias  = (const float*)d_in[2];
  const float* W_qkv    = (const float*)d_in[3];
  const float* b_qkv    = (const float*)d_in[4];
  const float* W_out    = (const float*)d_in[5];
  const float* b_out    = (const float*)d_in[6];
  float* out = (float*)d_out;

  char* ws = (char*)d_ws;
  bf16_t* h_t   = (bf16_t*)(ws);               // 8 MiB  [b][s][c]
  bf16_t* qk_t  = (bf16_t*)(ws + 8388608);     // 16 MiB [b][s][h*128+det]
  bf16_t* vt    = (bf16_t*)(ws + 25165824);    // 8 MiB  [b][h][dv][s]
  bf16_t* ao_t  = (bf16_t*)(ws + 33554432);    // 8 MiB  [b][s][c]
  bf16_t* wqkvp = (bf16_t*)(ws + 41943040);    // 1.5 MiB [d'][c] permuted
  bf16_t* woutt = (bf16_t*)(ws + 43515904);    // 0.5 MiB [d][c]
  float* bqp = (float*)d_out;  // 1536 f32 bias, overwritten later by gemm_out

  hipFuncSetAttribute((const void*)attn_kernel,
                      hipFuncAttributeMaxDynamicSharedMemorySize, 98304);

  prep_kernel<<<1280, 256, 0, stream>>>(x, gn_scale, gn_bias, W_qkv, b_qkv,
                                        W_out, h_t, wqkvp, woutt, bqp);
  gemm_qkv_kernel<<<768, 256, 0, stream>>>(h_t, wqkvp, bqp, qk_t, vt);
  attn_kernel<<<256, 512, 98304, stream>>>(qk_t, vt, ao_t);
  gemm_out_kernel<<<512, 256, 0, stream>>>(ao_t, woutt, b_out, x, out);
}

// Round 9
// 75.643 us; speedup vs baseline: 1.0255x; 1.0214x over previous
//
#include <hip/hip_runtime.h>
#include <hip/hip_bf16.h>

typedef __bf16 bf16_t;
typedef __attribute__((ext_vector_type(8))) __bf16 bf16x8;
typedef __attribute__((ext_vector_type(4))) float f32x4;
typedef __attribute__((ext_vector_type(4))) unsigned int u32x4;

#define B_   8
#define C_   512
#define S_   1024
#define NH   8
#define C2_  1024
#define C3_  1536
#define QSCALE 0.1803368801111204f  // 0.125 * log2(e): softmax in exp2 domain

static __device__ __forceinline__ unsigned pack2(float a, float b) {
  unsigned short lo = __builtin_bit_cast(unsigned short, (bf16_t)a);
  unsigned short hi = __builtin_bit_cast(unsigned short, (bf16_t)b);
  return (unsigned)lo | ((unsigned)hi << 16);
}

static __device__ __forceinline__ void load_lds16(const void* g, void* l) {
  __builtin_amdgcn_global_load_lds(
      (const __attribute__((address_space(1))) unsigned*)g,
      (__attribute__((address_space(3))) unsigned*)l, 16, 0, 0);
}

// Stage ROUNDS*256 16B chunks into LDS (256-thread blocks). Rows are 128B
// (8 chunks); source chunk XOR-swizzled (c ^ row&7) so ds_read_b128 frags
// are conflict-free while the LDS dest stays linear (m173 pattern).
template<int ROUNDS>
static __device__ __forceinline__ void stage_swz(const bf16_t* g, int rstride,
                                                 char* lbuf, int tid) {
#pragma unroll
  for (int r = 0; r < ROUNDS; ++r) {
    int i = r * 256 + tid;
    int row = i >> 3;
    int cg = (i & 7) ^ (row & 7);
    load_lds16(g + (size_t)row * rstride + cg * 8,
               lbuf + r * 4096 + (tid & 192) * 16);  // wave-uniform base
  }
}

// 512-thread variant: one round covers 512 chunks = 64 rows = 8 KB.
static __device__ __forceinline__ void stage_swz512(const bf16_t* g, int rstride,
                                                    char* lbuf, int tid) {
  int row = tid >> 3;
  int cg = (tid & 7) ^ (row & 7);
  load_lds16(g + (size_t)row * rstride + cg * 8,
             lbuf + (tid & 448) * 16);  // wave-uniform base
}

// ---------------------------------------------------------------------------
// Merged prep: [0,256) GroupNorm+transpose, [256,1024) W_qkv prep,
// [1024,1280) W_out transpose.
// ---------------------------------------------------------------------------
__global__ __launch_bounds__(256) void prep_kernel(
    const float* __restrict__ x, const float* __restrict__ gsc,
    const float* __restrict__ gbi, const float* __restrict__ Wq,
    const float* __restrict__ bq, const float* __restrict__ Wo,
    bf16_t* __restrict__ h_t, bf16_t* __restrict__ wqkvp,
    bf16_t* __restrict__ woutt, float* __restrict__ bqp) {
  __shared__ __align__(16) char smem[65568];
  int bid = blockIdx.x;
  int tid = threadIdx.x;
  if (bid < 256) {
    // ---- GroupNorm + bf16 + transpose: x[b][c][s] -> h_t[b][s][c]
    float* xs = (float*)smem;
    float* red = (float*)(smem + 65536);
    int b = bid >> 5, g = bid & 31;
    const f32x4* xb4 = (const f32x4*)(x + ((size_t)b * C_ + g * 16) * S_);
    float s = 0.f, s2 = 0.f;
#pragma unroll
    for (int k = 0; k < 16; ++k) {
      int vf = k * 256 + tid;
      f32x4 v = xb4[vf];
      ((f32x4*)xs)[vf] = v;
#pragma unroll
      for (int e = 0; e < 4; ++e) { s += v[e]; s2 += v[e] * v[e]; }
    }
    for (int off = 32; off > 0; off >>= 1) {
      s  += __shfl_down(s, off);
      s2 += __shfl_down(s2, off);
    }
    int wave = tid >> 6, lane = tid & 63;
    if (lane == 0) { red[wave] = s; red[4 + wave] = s2; }
    __syncthreads();
    float ts = red[0] + red[1] + red[2] + red[3];
    float t2 = red[4] + red[5] + red[6] + red[7];
    const float inv_n = 1.f / (16.f * S_);
    float mean = ts * inv_n;
    float var  = t2 * inv_n - mean * mean;
    float rstd = rsqrtf(var + 1e-6f);
    float ac[16], bc[16];
#pragma unroll
    for (int cl = 0; cl < 16; ++cl) {
      float sc = gsc[g * 16 + cl] * rstd;
      ac[cl] = sc;
      bc[cl] = gbi[g * 16 + cl] - mean * sc;
    }
#pragma unroll
    for (int k = 0; k < 4; ++k) {
      int srow = tid + k * 256;
      unsigned ow[8];
#pragma unroll
      for (int p = 0; p < 8; ++p) {
        float y0 = xs[(2 * p    ) * 1024 + srow] * ac[2 * p    ] + bc[2 * p    ];
        float y1 = xs[(2 * p + 1) * 1024 + srow] * ac[2 * p + 1] + bc[2 * p + 1];
        ow[p] = pack2(y0, y1);
      }
      bf16_t* dst = h_t + ((size_t)b * S_ + srow) * C_ + g * 16;
      u32x4 v0, v1;
#pragma unroll
      for (int e = 0; e < 4; ++e) { v0[e] = ow[e]; v1[e] = ow[4 + e]; }
      *(u32x4*)dst = v0;
      *(u32x4*)(dst + 8) = v1;
    }
  } else if (bid < 1024) {
    // ---- W_qkv: transpose + permute d->d'=part*512+h*64+dq, fold QSCALE
    float* T = (float*)smem;
    int id = bid - 256;
    int d0 = (id % 48) * 32, c0 = (id / 48) * 32;
    int ld = tid & 31, lc = tid >> 5;
#pragma unroll
    for (int i = 0; i < 4; ++i) {
      int c = lc + i * 8;
      T[c * 33 + ld] = Wq[(size_t)(c0 + c) * C3_ + d0 + ld];
    }
    __syncthreads();
#pragma unroll
    for (int i = 0; i < 4; ++i) {
      int dd = lc + i * 8;
      int d = d0 + dd;
      int h = d / 192, rr = d - h * 192, part = rr >> 6, dq = rr & 63;
      float scl = (part == 0) ? QSCALE : 1.f;
      wqkvp[(size_t)(part * 512 + h * 64 + dq) * C_ + c0 + ld] =
          (bf16_t)(T[ld * 33 + dd] * scl);
    }
    if (id < 48 && tid < 32) {
      int d = d0 + tid;
      int h = d / 192, rr = d - h * 192, part = rr >> 6, dq = rr & 63;
      bqp[part * 512 + h * 64 + dq] = bq[d] * ((part == 0) ? QSCALE : 1.f);
    }
  } else {
    // ---- W_out transpose: Wo[512 c][512 d] f32 -> woutt[d][c] bf16
    float* T = (float*)smem;
    int id = bid - 1024;
    int c0 = (id & 15) * 32, r0 = (id >> 4) * 32;
    int lc = tid & 31, lr = tid >> 5;
#pragma unroll
    for (int i = 0; i < 4; ++i) {
      int r = lr + i * 8;
      T[r * 33 + lc] = Wo[(size_t)(r0 + r) * C_ + c0 + lc];
    }
    __syncthreads();
#pragma unroll
    for (int i = 0; i < 4; ++i) {
      int cc = lr + i * 8;
      woutt[(size_t)(c0 + cc) * C_ + r0 + lc] = (bf16_t)T[lc * 33 + cc];
    }
  }
}

// ---------------------------------------------------------------------------
// Templated staged-GEMM mainloop: C[MF*32 m][NF*32 n] = A[m][k]*B[n][k], K=512.
// BK=64, double-buffered global_load_lds staging, counted vmcnt, raw barriers.
// 256 threads as 2x2 waves; per wave MF x NF 16x16 frags.
// ---------------------------------------------------------------------------
template<int MF, int NF>
static __device__ __forceinline__ void gemm_loop(
    const bf16_t* Asrc, int Astride, const bf16_t* Bsrc, int Bstride,
    char* lds, int tid, f32x4 (&acc)[MF][NF]) {
  int wave = tid >> 6, lane = tid & 63;
  int wr = wave >> 1, wc = wave & 1;
  int lr = lane & 15, lq = lane >> 4;
  char* A0 = lds;
  char* B0 = lds + MF * 4096;
  char* A1 = lds + (MF + NF) * 4096;
  char* B1 = lds + (2 * MF + NF) * 4096;
  stage_swz<MF>(Asrc, Astride, A0, tid);
  stage_swz<NF>(Bsrc, Bstride, B0, tid);
#pragma unroll 1
  for (int ks = 0; ks < 8; ++ks) {
    if (ks < 7) {
      stage_swz<MF>(Asrc + (ks + 1) * 64, Astride, (ks & 1) ? A0 : A1, tid);
      stage_swz<NF>(Bsrc + (ks + 1) * 64, Bstride, (ks & 1) ? B0 : B1, tid);
      asm volatile("s_waitcnt vmcnt(%0)" :: "i"(MF + NF) : "memory");
    } else {
      asm volatile("s_waitcnt vmcnt(0)" ::: "memory");
    }
    __builtin_amdgcn_s_barrier();
    const char* Ab = (ks & 1) ? A1 : A0;
    const char* Bb = (ks & 1) ? B1 : B0;
#pragma unroll
    for (int kk = 0; kk < 2; ++kk) {
      int co = ((kk * 4 + lq) ^ (lr & 7)) << 4;
      bf16x8 a[MF], b[NF];
#pragma unroll
      for (int i = 0; i < MF; ++i)
        a[i] = *(const bf16x8*)(Ab + (wr * MF * 16 + i * 16 + lr) * 128 + co);
#pragma unroll
      for (int j = 0; j < NF; ++j)
        b[j] = *(const bf16x8*)(Bb + (wc * NF * 16 + j * 16 + lr) * 128 + co);
#pragma unroll
      for (int i = 0; i < MF; ++i)
#pragma unroll
        for (int j = 0; j < NF; ++j)
          acc[i][j] = __builtin_amdgcn_mfma_f32_16x16x32_bf16(a[i], b[j], acc[i][j], 0, 0, 0);
    }
    __builtin_amdgcn_s_barrier();
  }
}

// ---------------------------------------------------------------------------
// Merged QKV projection. 1-D grid, 768 blocks, XCD-grouped (same h_t panel
// -> same XCD). bid<512: QK role -> qk[b][s][h*128+det]; else V role
// (swapped operands) -> vt[b][h][dv][s].
// ---------------------------------------------------------------------------
__global__ __launch_bounds__(256) void gemm_qkv_kernel(
    const bf16_t* __restrict__ h, const bf16_t* __restrict__ wq,
    const float* __restrict__ bias, bf16_t* __restrict__ qk,
    bf16_t* __restrict__ vt) {
  __shared__ char lds[65536];
  int tid = threadIdx.x;
  int bid = blockIdx.x;
  int wave = tid >> 6, lane = tid & 63;
  int wr = wave >> 1, wc = wave & 1, lr = lane & 15, lq = lane >> 4;
  unsigned short* tb = (unsigned short*)lds;
  if (bid < 512) {
    int m0 = (bid & 63) * 128, n0 = (bid >> 6) * 128;
    f32x4 acc[4][4] = {};
    gemm_loop<4, 4>(h + (size_t)m0 * C_, C_, wq + (size_t)n0 * C_, C_, lds, tid, acc);
    float bv[4];
#pragma unroll
    for (int j = 0; j < 4; ++j) bv[j] = bias[n0 + wc * 64 + j * 16 + lr];
#pragma unroll
    for (int i = 0; i < 4; ++i)
#pragma unroll
      for (int j = 0; j < 4; ++j)
#pragma unroll
        for (int r = 0; r < 4; ++r) {
          int row = wr * 64 + i * 16 + lq * 4 + r;
          int col = wc * 64 + j * 16 + lr;
          int byte = row * 256 + (((col >> 3) ^ (row & 7)) << 4) + ((col & 7) << 1);
          tb[byte >> 1] = __builtin_bit_cast(unsigned short, (bf16_t)(acc[i][j][r] + bv[j]));
        }
    __builtin_amdgcn_s_barrier();
#pragma unroll
    for (int u = 0; u < 8; ++u) {
      int flat = tid + u * 256;
      int row = flat >> 4, c = flat & 15;
      u32x4 v = *(const u32x4*)(lds + row * 256 + ((c ^ (row & 7)) << 4));
      int m = m0 + row, b = m >> 10, s = m & 1023;
      int d = n0 + c * 8;
      int hh = (d >> 6) & 7, det = ((d >> 9) << 6) + (d & 63);
      *(u32x4*)(qk + ((size_t)(b * S_ + s)) * C2_ + hh * 128 + det) = v;
    }
  } else {
    int j2 = bid - 512;
    int n0 = (j2 & 63) * 128, m0 = (j2 >> 6) * 128;
    f32x4 acc[4][4] = {};
    gemm_loop<4, 4>(wq + (size_t)(1024 + m0) * C_, C_, h + (size_t)n0 * C_, C_, lds, tid, acc);
    float bv[4][4];
#pragma unroll
    for (int i = 0; i < 4; ++i) {
      f32x4 t = *(const f32x4*)(bias + 1024 + m0 + wr * 64 + i * 16 + lq * 4);
#pragma unroll
      for (int r = 0; r < 4; ++r) bv[i][r] = t[r];
    }
#pragma unroll
    for (int i = 0; i < 4; ++i)
#pragma unroll
      for (int j = 0; j < 4; ++j)
#pragma unroll
        for (int r = 0; r < 4; ++r) {
          int row = wr * 64 + i * 16 + lq * 4 + r;
          int col = wc * 64 + j * 16 + lr;
          int byte = row * 256 + (((col >> 3) ^ (row & 7)) << 4) + ((col & 7) << 1);
          tb[byte >> 1] = __builtin_bit_cast(unsigned short, (bf16_t)(acc[i][j][r] + bv[i][r]));
        }
    __builtin_amdgcn_s_barrier();
#pragma unroll
    for (int u = 0; u < 8; ++u) {
      int flat = tid + u * 256;
      int row = flat >> 4, c = flat & 15;
      u32x4 v = *(const u32x4*)(lds + row * 256 + ((c ^ (row & 7)) << 4));
      int m = m0 + row;  // h*64+dv
      int hh = m >> 6, dv = m & 63;
      int n = n0 + c * 8, b = n >> 10, s = n & 1023;
      *(u32x4*)(vt + ((size_t)((b * NH + hh) * 64 + dv)) * S_ + s) = v;
    }
  }
}

// ---------------------------------------------------------------------------
// Flash attention. 256 blocks x 512 threads (8 waves x 32 q-rows), KBLK=64,
// 4 LDS buffers indexed by tile (buf[t&3]), 2-deep prefetch, counted vmcnt.
// LAG-1 PV PIPELINE (T15): iteration kt issues QK^T(kt), then PV(kt-1)
// (pk_prev + V from buf[(kt-1)&3] -- distance-3 from the stage target so no
// race), then softmax(kt) on the VALU under the PV MFMA shadow. PV(kt-1)
// lands in oacc BEFORE kt's deferred rescale -> numerics identical.
// ---------------------------------------------------------------------------
__global__ __launch_bounds__(512) void attn_kernel(
    const bf16_t* __restrict__ qk, const bf16_t* __restrict__ vt,
    bf16_t* __restrict__ ao) {
  __shared__ char lds[65536];
  int bid = blockIdx.x;
  int qt = bid >> 6, g = bid & 63;
  int b = g >> 3, head = g & 7;
  int tid = threadIdx.x, wave = tid >> 6, lane = tid & 63;
  int lr = lane & 15, lq = lane >> 4;
  int qb = qt * 256 + wave * 32;
  const bf16_t* qkb = qk + (size_t)b * S_ * C2_ + head * 128;
  const bf16_t* vtb = vt + (size_t)((b * NH + head) * 64) * S_;

  bf16x8 qf[2][2];
#pragma unroll
  for (int q2 = 0; q2 < 2; ++q2)
#pragma unroll
    for (int kk = 0; kk < 2; ++kk)
      qf[q2][kk] = *(const bf16x8*)(qkb + (size_t)(qb + q2 * 16 + lr) * C2_ + kk * 32 + lq * 8);

  f32x4 oacc[2][4] = {};
  float m_run[2] = {-1e30f, -1e30f}, l_run[2] = {0.f, 0.f};
  unsigned pkp[2][4][2];  // P of previous tile (bf16-pair packed)

#define STAGE_KV(kt)                                                         \
  do {                                                                       \
    char* buf_ = lds + (((kt) & 3) << 14);                                   \
    stage_swz512(qkb + (size_t)((kt) * 64) * C2_ + 64, C2_, buf_, tid);      \
    stage_swz512(vtb + (kt) * 64, S_, buf_ + 8192, tid);                     \
  } while (0)

// PV for tile (t) using pkp, V from buf[t&3]
#define PV_STEP(t)                                                           \
  do {                                                                       \
    char* vb_ = lds + (((t) & 3) << 14) + 8192;                              \
    _Pragma("unroll")                                                        \
    for (int kk = 0; kk < 2; ++kk) {                                         \
      int co_ = ((kk * 4 + lq) ^ (lr & 7)) << 4;                             \
      bf16x8 vf_[4];                                                         \
      _Pragma("unroll")                                                      \
      for (int df = 0; df < 4; ++df)                                         \
        vf_[df] = *(const bf16x8*)(vb_ + (df * 16 + lr) * 128 + co_);        \
      _Pragma("unroll")                                                      \
      for (int q2 = 0; q2 < 2; ++q2) {                                       \
        unsigned w0 = pkp[q2][2 * kk + 0][0], w2 = pkp[q2][2 * kk + 1][0];   \
        unsigned w1 = pkp[q2][2 * kk + 0][1], w3 = pkp[q2][2 * kk + 1][1];   \
        asm("v_permlane32_swap_b32 %0, %1" : "+v"(w0), "+v"(w2));            \
        asm("v_permlane16_swap_b32 %0, %1" : "+v"(w0), "+v"(w2));            \
        asm("v_permlane32_swap_b32 %0, %1" : "+v"(w1), "+v"(w3));            \
        asm("v_permlane16_swap_b32 %0, %1" : "+v"(w1), "+v"(w3));            \
        u32x4 bw_; bw_[0] = w0; bw_[1] = w1; bw_[2] = w2; bw_[3] = w3;       \
        bf16x8 pb_ = __builtin_bit_cast(bf16x8, bw_);                        \
        _Pragma("unroll")                                                    \
        for (int df = 0; df < 4; ++df)                                       \
          oacc[q2][df] = __builtin_amdgcn_mfma_f32_16x16x32_bf16(            \
              vf_[df], pb_, oacc[q2][df], 0, 0, 0);                          \
      }                                                                      \
    }                                                                        \
  } while (0)

  STAGE_KV(0);
  STAGE_KV(1);
#pragma unroll 1
  for (int kt = 0; kt < 16; ++kt) {
    if (kt < 15) {
      asm volatile("s_waitcnt vmcnt(4)" ::: "memory");
    } else {
      asm volatile("s_waitcnt vmcnt(0)" ::: "memory");
    }
    __builtin_amdgcn_s_barrier();
    if (kt < 14) STAGE_KV(kt + 2);  // target buf[(kt+2)&3]: last read kt-1

    // S^T = K Q^T from buf[kt&3]  (Q pre-scaled by 0.125*log2e)
    char* kb = lds + ((kt & 3) << 14);
    f32x4 sacc[2][4] = {};
    __builtin_amdgcn_s_setprio(1);
#pragma unroll
    for (int kk = 0; kk < 2; ++kk) {
      int co = ((kk * 4 + lq) ^ (lr & 7)) << 4;
      bf16x8 kf[4];
#pragma unroll
      for (int mf = 0; mf < 4; ++mf)
        kf[mf] = *(const bf16x8*)(kb + (mf * 16 + lr) * 128 + co);
#pragma unroll
      for (int q2 = 0; q2 < 2; ++q2)
#pragma unroll
        for (int mf = 0; mf < 4; ++mf)
          sacc[q2][mf] = __builtin_amdgcn_mfma_f32_16x16x32_bf16(kf[mf], qf[q2][kk], sacc[q2][mf], 0, 0, 0);
    }

    // PV of PREVIOUS tile -- MFMA shadow under which softmax(kt) executes
    if (kt > 0) PV_STEP(kt - 1);
    __builtin_amdgcn_s_setprio(0);

    // softmax(kt): max-reduce, defer-rescale, exp2, pack -> pkp
    float mx[2];
#pragma unroll
    for (int q2 = 0; q2 < 2; ++q2) {
      float m = -1e30f;
#pragma unroll
      for (int mf = 0; mf < 4; ++mf)
#pragma unroll
        for (int r = 0; r < 4; ++r) m = fmaxf(m, sacc[q2][mf][r]);
      m = fmaxf(m, __shfl_xor(m, 16));
      m = fmaxf(m, __shfl_xor(m, 32));
      mx[q2] = m;
    }
    if (__any(fmaxf(mx[0] - m_run[0], mx[1] - m_run[1]) > 11.f)) {  // T13
#pragma unroll
      for (int q2 = 0; q2 < 2; ++q2) {
        float mn = fmaxf(m_run[q2], mx[q2]);
        float alpha = __builtin_amdgcn_exp2f(m_run[q2] - mn);
        m_run[q2] = mn;
        l_run[q2] *= alpha;
#pragma unroll
        for (int df = 0; df < 4; ++df)
#pragma unroll
          for (int r = 0; r < 4; ++r) oacc[q2][df][r] *= alpha;
      }
    }
#pragma unroll
    for (int q2 = 0; q2 < 2; ++q2) {
      float rs = 0.f;
#pragma unroll
      for (int mf = 0; mf < 4; ++mf) {
        float p0 = __builtin_amdgcn_exp2f(sacc[q2][mf][0] - m_run[q2]);
        float p1 = __builtin_amdgcn_exp2f(sacc[q2][mf][1] - m_run[q2]);
        float p2 = __builtin_amdgcn_exp2f(sacc[q2][mf][2] - m_run[q2]);
        float p3 = __builtin_amdgcn_exp2f(sacc[q2][mf][3] - m_run[q2]);
        rs += (p0 + p1) + (p2 + p3);
        pkp[q2][mf][0] = pack2(p0, p1);
        pkp[q2][mf][1] = pack2(p2, p3);
      }
      l_run[q2] += rs;                     // per-lane partial; reduced at end
    }
  }

  // drain the pipeline: PV of the last tile
  __builtin_amdgcn_s_setprio(1);
  PV_STEP(15);
  __builtin_amdgcn_s_setprio(0);

  // epilogue: reduce per-lane l partials, write O^T
#pragma unroll
  for (int q2 = 0; q2 < 2; ++q2) {
    float lt = l_run[q2];
    lt += __shfl_xor(lt, 16);
    lt += __shfl_xor(lt, 32);
    float inv = 1.f / lt;
    bf16_t* aop = ao + ((size_t)b * S_ + qb + q2 * 16 + lr) * C_ + head * 64;
#pragma unroll
    for (int df = 0; df < 4; ++df)
#pragma unroll
      for (int rp = 0; rp < 4; rp += 2) {
        unsigned u = pack2(oacc[q2][df][rp] * inv, oacc[q2][df][rp + 1] * inv);
        *(unsigned*)(aop + df * 16 + lq * 4 + rp) = u;
      }
  }
#undef STAGE_KV
#undef PV_STEP
}

// ---------------------------------------------------------------------------
// Out projection + bias + residual: out[b][d][s] = x + b_out[d] + ao @ W_out
// 512 blocks, 64m x 128n tiles; bid = n*128 + m (same-ao-panel -> same XCD).
// ---------------------------------------------------------------------------
__global__ __launch_bounds__(256) void gemm_out_kernel(
    const bf16_t* __restrict__ A, const bf16_t* __restrict__ Bw,
    const float* __restrict__ bias, const float* __restrict__ xres,
    float* __restrict__ out) {
  __shared__ char lds[49152];
  int tid = threadIdx.x;
  int bid = blockIdx.x;
  int m0 = (bid & 127) * 64, n0 = (bid >> 7) * 128;
  f32x4 acc[2][4] = {};
  gemm_loop<2, 4>(A + (size_t)m0 * C_, C_, Bw + (size_t)n0 * C_, C_, lds, tid, acc);
  int wave = tid >> 6, lane = tid & 63;
  int wr = wave >> 1, wc = wave & 1, lr = lane & 15, lq = lane >> 4;
#pragma unroll
  for (int i = 0; i < 2; ++i) {
#pragma unroll
    for (int j = 0; j < 4; ++j) {
      int d = n0 + wc * 64 + j * 16 + lr;
      int m = m0 + wr * 32 + i * 16 + lq * 4;
      int b = m >> 10, s = m & 1023;
      size_t o = ((size_t)b * C_ + d) * S_ + s;
      f32x4 res = *(const f32x4*)(xres + o);
      f32x4 val;
      float bd = bias[d];
#pragma unroll
      for (int r = 0; r < 4; ++r) val[r] = res[r] + bd + acc[i][j][r];
      *(f32x4*)(out + o) = val;
    }
  }
}

// ---------------------------------------------------------------------------
extern "C" void kernel_launch(void* const* d_in, const int* in_sizes, int n_in,
                              void* d_out, int out_size, void* d_ws, size_t ws_size,
                              hipStream_t stream) {
  const float* x        = (const float*)d_in[0];
  const float* gn_scale = (const float*)d_in[1];
  const float* gn_bias  = (const float*)d_in[2];
  const float* W_qkv    = (const float*)d_in[3];
  const float* b_qkv    = (const float*)d_in[4];
  const float* W_out    = (const float*)d_in[5];
  const float* b_out    = (const float*)d_in[6];
  float* out = (float*)d_out;

  char* ws = (char*)d_ws;
  bf16_t* h_t   = (bf16_t*)(ws);               // 8 MiB  [b][s][c]
  bf16_t* qk_t  = (bf16_t*)(ws + 8388608);     // 16 MiB [b][s][h*128+det]
  bf16_t* vt    = (bf16_t*)(ws + 25165824);    // 8 MiB  [b][h][dv][s]
  bf16_t* ao_t  = (bf16_t*)(ws + 33554432);    // 8 MiB  [b][s][c]
  bf16_t* wqkvp = (bf16_t*)(ws + 41943040);    // 1.5 MiB [d'][c] permuted
  bf16_t* woutt = (bf16_t*)(ws + 43515904);    // 0.5 MiB [d][c]
  float* bqp = (float*)d_out;  // 1536 f32 bias, overwritten later by gemm_out

  prep_kernel<<<1280, 256, 0, stream>>>(x, gn_scale, gn_bias, W_qkv, b_qkv,
                                        W_out, h_t, wqkvp, woutt, bqp);
  gemm_qkv_kernel<<<768, 256, 0, stream>>>(h_t, wqkvp, bqp, qk_t, vt);
  attn_kernel<<<256, 512, 0, stream>>>(qk_t, vt, ao_t);
  gemm_out_kernel<<<512, 256, 0, stream>>>(ao_t, woutt, b_out, x, out);
}